// Round 1
// baseline (833.801 us; speedup 1.0000x reference)
//
#include <hip/hip_runtime.h>

// Weisfeiler-Lehman conv, factorized:
//   out[b,c,n,k] = Y0 + e1[c,k]*Y1 + e2[c,k]*Y2 + e3[c,k]*Y3,  Ym = M^m labels
// where M = (ligand >= 1) adjacency acting on the node dim, and e_m are the
// elementary symmetric polynomials of kernels[c,0..2,k]. Valid because the
// per-step ops (I + k_t∘M) all commute (k-scaling is node-independent).
//
// Buffers:
//   d_out (8 MB)  : reused as packed bit-mask scratch (exactly B*N*N/8 bytes),
//                   overwritten by the final combine kernel.
//   d_ws  (3 MB)  : Y1|Y2|Y3, each B*N*K f32 (1 MB). Requires ws_size >= 3 MB.

#define BB 4
#define NN 4096
#define KK 16
#define CC 8
#define TT 3
#define WPR (NN / 64)   // 64-bit words per adjacency row

typedef unsigned long long u64;

// ---------------------------------------------------------------- pack ------
// bits[(b*NN+n)*WPR + w] bit j  <->  mask[b][n][w*64+j]
__global__ void pack_kernel(const int* __restrict__ lig, u64* __restrict__ bits) {
    const long total = (long)BB * NN * WPR;              // 1,048,576 words
    long wid  = ((long)blockIdx.x * blockDim.x + threadIdx.x) >> 6;
    int  lane = threadIdx.x & 63;
    long nw   = ((long)gridDim.x * blockDim.x) >> 6;
    for (long c = wid; c < total; c += nw) {
        int v = lig[(c << 6) | lane];                    // coalesced dword
        u64 m = __ballot(v >= 1);
        if (lane == 0) bits[c] = m;
    }
}

// ---------------------------------------------------------------- spmm ------
// yout += M_chunk * yin  over one s-chunk; yout must be pre-zeroed.
// grid: BB * (NN/1024) * SCHUNKS blocks of 256 threads.
// Each thread: 4 rows x 16 k accumulators; Y chunk staged in LDS; all lanes
// read the same LDS address per s (broadcast, conflict-free).
#define SCHUNKS 16
#define SLEN 256
#define RPT 4
#define ROWS_PER_BLOCK (256 * RPT)   // 1024

__global__ void spmm_kernel(const u64* __restrict__ bits,
                            const float* __restrict__ yin,
                            float* __restrict__ yout) {
    __shared__ float ys[SLEN * KK];                      // 16 KB
    int bid = blockIdx.x;
    int sc  = bid & (SCHUNKS - 1);
    int rb  = (bid >> 4) & 3;                            // NN/ROWS_PER_BLOCK = 4
    int b   = bid >> 6;
    int tid = threadIdx.x;
    int s0  = sc * SLEN;

    // stage Y[s0 .. s0+255][0..15] into LDS (coalesced float4)
    const float4* ysrc = (const float4*)(yin + ((long)b * NN + s0) * KK);
    float4* ydst = (float4*)ys;
    for (int i = tid; i < SLEN * KK / 4; i += 256) ydst[i] = ysrc[i];
    __syncthreads();

    int row0 = rb * ROWS_PER_BLOCK + tid * RPT;
    const u64* wrow = bits + ((long)b * NN + row0) * WPR + (s0 >> 6);

    float acc[RPT][KK];
#pragma unroll
    for (int r = 0; r < RPT; ++r)
#pragma unroll
        for (int k = 0; k < KK; ++k) acc[r][k] = 0.f;

#pragma unroll 1
    for (int w = 0; w < SLEN / 64; ++w) {
        u64 m[RPT];
#pragma unroll
        for (int r = 0; r < RPT; ++r) m[r] = wrow[(long)r * WPR + w];
#pragma unroll 4
        for (int j = 0; j < 64; ++j) {
            const float* y = &ys[(w * 64 + j) * KK];
            float4 y0 = ((const float4*)y)[0];
            float4 y1 = ((const float4*)y)[1];
            float4 y2 = ((const float4*)y)[2];
            float4 y3 = ((const float4*)y)[3];
#pragma unroll
            for (int r = 0; r < RPT; ++r) {
                float f = (float)((m[r] >> j) & 1ull);
                acc[r][0]  += f * y0.x; acc[r][1]  += f * y0.y;
                acc[r][2]  += f * y0.z; acc[r][3]  += f * y0.w;
                acc[r][4]  += f * y1.x; acc[r][5]  += f * y1.y;
                acc[r][6]  += f * y1.z; acc[r][7]  += f * y1.w;
                acc[r][8]  += f * y2.x; acc[r][9]  += f * y2.y;
                acc[r][10] += f * y2.z; acc[r][11] += f * y2.w;
                acc[r][12] += f * y3.x; acc[r][13] += f * y3.y;
                acc[r][14] += f * y3.z; acc[r][15] += f * y3.w;
            }
        }
    }

    float* yo = yout + ((long)b * NN + row0) * KK;
#pragma unroll
    for (int r = 0; r < RPT; ++r)
#pragma unroll
        for (int k = 0; k < KK; ++k)
            atomicAdd(&yo[r * KK + k], acc[r][k]);
}

// -------------------------------------------------------------- combine -----
// out[b][c][n][k] = Y0 + e1*Y1 + e2*Y2 + e3*Y3
__global__ void combine_kernel(const float* __restrict__ Y0,
                               const float* __restrict__ Yc,   // Y1|Y2|Y3
                               const float* __restrict__ ker,  // [C][T][K]
                               float* __restrict__ out) {
    __shared__ float4 eS[3][CC][KK / 4];
    int tid = threadIdx.x;
    if (tid < CC * (KK / 4)) {
        int c = tid >> 2, k4 = tid & 3;
        const float4* kf = (const float4*)ker;
        float4 a = kf[(c * TT + 0) * (KK / 4) + k4];
        float4 d = kf[(c * TT + 1) * (KK / 4) + k4];
        float4 e = kf[(c * TT + 2) * (KK / 4) + k4];
        float4 e1, e2, e3;
        e1.x = a.x + d.x + e.x;           e1.y = a.y + d.y + e.y;
        e1.z = a.z + d.z + e.z;           e1.w = a.w + d.w + e.w;
        e2.x = a.x*d.x + a.x*e.x + d.x*e.x; e2.y = a.y*d.y + a.y*e.y + d.y*e.y;
        e2.z = a.z*d.z + a.z*e.z + d.z*e.z; e2.w = a.w*d.w + a.w*e.w + d.w*e.w;
        e3.x = a.x * d.x * e.x;           e3.y = a.y * d.y * e.y;
        e3.z = a.z * d.z * e.z;           e3.w = a.w * d.w * e.w;
        eS[0][c][k4] = e1; eS[1][c][k4] = e2; eS[2][c][k4] = e3;
    }
    __syncthreads();

    int gid = blockIdx.x * blockDim.x + tid;
    if (gid >= BB * NN * (KK / 4)) return;
    int k4 = gid & 3;
    int n  = (gid >> 2) & (NN - 1);
    int b  = gid >> 14;
    const long YSZ = (long)BB * NN * KK / 4;
    long yi = (long)(b * NN + n) * (KK / 4) + k4;
    float4 y0 = ((const float4*)Y0)[yi];
    float4 y1 = ((const float4*)Yc)[yi];
    float4 y2 = ((const float4*)Yc)[YSZ + yi];
    float4 y3 = ((const float4*)Yc)[2 * YSZ + yi];
#pragma unroll
    for (int c = 0; c < CC; ++c) {
        float4 e1 = eS[0][c][k4], e2 = eS[1][c][k4], e3 = eS[2][c][k4];
        float4 r;
        r.x = y0.x + e1.x * y1.x + e2.x * y2.x + e3.x * y3.x;
        r.y = y0.y + e1.y * y1.y + e2.y * y2.y + e3.y * y3.y;
        r.z = y0.z + e1.z * y1.z + e2.z * y2.z + e3.z * y3.z;
        r.w = y0.w + e1.w * y1.w + e2.w * y2.w + e3.w * y3.w;
        ((float4*)out)[(long)((b * CC + c) * NN + n) * (KK / 4) + k4] = r;
    }
}

// --------------------------------------------------------------- launch -----
extern "C" void kernel_launch(void* const* d_in, const int* in_sizes, int n_in,
                              void* d_out, int out_size, void* d_ws, size_t ws_size,
                              hipStream_t stream) {
    const float* labels = (const float*)d_in[0];   // [B,N,K] f32
    const int*   lig    = (const int*)d_in[1];     // [B,N,N] i32
    const float* ker    = (const float*)d_in[2];   // [C,T,K] f32
    float* out = (float*)d_out;
    u64*   bits = (u64*)d_out;                     // 8 MB scratch, exact fit
    float* Y1 = (float*)d_ws;                      // B*N*K each
    float* Y2 = Y1 + (long)BB * NN * KK;
    float* Y3 = Y2 + (long)BB * NN * KK;

    hipLaunchKernelGGL(pack_kernel, dim3(2048), dim3(256), 0, stream, lig, bits);
    hipMemsetAsync(d_ws, 0, 3L * BB * NN * KK * sizeof(float), stream);

    dim3 sgrid(BB * (NN / ROWS_PER_BLOCK) * SCHUNKS);  // 256 blocks
    hipLaunchKernelGGL(spmm_kernel, sgrid, dim3(256), 0, stream, bits, labels, Y1);
    hipLaunchKernelGGL(spmm_kernel, sgrid, dim3(256), 0, stream, bits, Y1, Y2);
    hipLaunchKernelGGL(spmm_kernel, sgrid, dim3(256), 0, stream, bits, Y2, Y3);

    hipLaunchKernelGGL(combine_kernel, dim3(BB * NN * (KK / 4) / 256), dim3(256),
                       0, stream, labels, Y1, ker, out);
}

// Round 2
// 470.044 us; speedup vs baseline: 1.7739x; 1.7739x over previous
//
#include <hip/hip_runtime.h>

// WL-conv factorized:  out[b,c,n,k] = Y0 + e1[c,k]*Y1 + e2[c,k]*Y2 + e3[c,k]*Y3
// with Ym = M^m labels (M = thresholded adjacency, c-independent) and e_m the
// elementary symmetric polynomials of kernels[c,0..2,k]. Valid because all
// per-step operators (I + k_t ∘ M) commute.
//
// d_out (8 MB): reused as TRANSPOSED packed bit-mask (word-major) scratch,
//               overwritten by the final combine kernel.
// d_ws (>=12 MB): Y1|Y2|Y3, each B*N*K f32.

#define BB 4
#define NN 4096
#define KK 16
#define CC 8
#define TT 3
#define WPR (NN / 64)

typedef unsigned long long u64;
typedef unsigned int u32;

// ---------------------------------------------------------------- pack ------
// TRANSPOSED: bits[(b*WPR + w)*NN + n] bit j <-> (lig[b][n][w*64+j] >= 1)
__global__ void pack_kernel(const int* __restrict__ lig, u64* __restrict__ bits) {
    const long total = (long)BB * WPR * NN;              // 1,048,576 words
    long wid  = ((long)blockIdx.x * blockDim.x + threadIdx.x) >> 6;
    int  lane = threadIdx.x & 63;
    long nw   = ((long)gridDim.x * blockDim.x) >> 6;
    for (long o = wid; o < total; o += nw) {
        int n = (int)(o & (NN - 1));
        int w = (int)((o >> 12) & (WPR - 1));
        int b = (int)(o >> 18);
        int v = lig[((long)b * NN + n) * NN + (w << 6) + lane];
        u64 m = __ballot(v >= 1);
        if (lane == 0) bits[o] = m;
    }
}

// ---------------------------------------------------------------- spmm ------
// yout += M * yin restricted to (row-block, s-chunk); yout pre-zeroed.
// grid = BB * (NN/ROWSB=16) * SCHUNKS=16 = 1024 blocks of 256 threads.
// lane layout: kh = bit0 (k-half), rg_lo = bits1-3, ss = bits4-5 (s-slice);
// wave W = tid>>6;  rg = W*8+rg_lo (32 groups x 8 rows = 256 rows/block).
// Each thread: 8 rows x 8 k accumulators over its 64-s word; ss-slices
// reduced with __shfl_xor(16/32); one atomicAdd per (row,k) per chunk.
#define SCHUNKS 16
#define SLEN 256
#define ROWSB 256

// y LDS layout: per 64-s block: 64*16 floats + 4 pad floats (breaks the
// ss-stride-4096B bank alias; b128 reads stay <=2-way which is free).
#define YSTRIDE 1028   // floats per 64-s block

__global__ __launch_bounds__(256, 4)
void spmm_kernel(const u64* __restrict__ bits,
                 const float* __restrict__ yin,
                 float* __restrict__ yout) {
    __shared__ float ys[4 * YSTRIDE];                    // 16448 B
    int bid = blockIdx.x;
    int sc  = bid & (SCHUNKS - 1);
    int rb  = (bid >> 4) & (NN / ROWSB - 1);
    int b   = bid >> 8;
    int tid = threadIdx.x;
    int s0  = sc * SLEN;

    // stage Y[s0..s0+255][0..15], padded every 64 s (float4 i -> i + (i>>8))
    const float4* ysrc = (const float4*)(yin + ((long)b * NN + s0) * KK);
    for (int i = tid; i < SLEN * KK / 4; i += 256)
        ((float4*)ys)[i + (i >> 8)] = ysrc[i];
    __syncthreads();

    const int kh    = tid & 1;
    const int rg_lo = (tid >> 1) & 7;
    const int ss    = (tid >> 4) & 3;
    const int W     = tid >> 6;
    const int rg    = W * 8 + rg_lo;
    const int row_base = rb * ROWSB + rg * 8;
    const int wglob = (s0 >> 6) + ss;

    // 8 consecutive row-masks for this word: one contiguous 64 B
    const ulonglong2* bp =
        (const ulonglong2*)(bits + (long)(b * WPR + wglob) * NN + row_base);
    ulonglong2 q0 = bp[0], q1 = bp[1], q2 = bp[2], q3 = bp[3];
    u32 lo[8], hi[8];
    lo[0] = (u32)q0.x; hi[0] = (u32)(q0.x >> 32);
    lo[1] = (u32)q0.y; hi[1] = (u32)(q0.y >> 32);
    lo[2] = (u32)q1.x; hi[2] = (u32)(q1.x >> 32);
    lo[3] = (u32)q1.y; hi[3] = (u32)(q1.y >> 32);
    lo[4] = (u32)q2.x; hi[4] = (u32)(q2.x >> 32);
    lo[5] = (u32)q2.y; hi[5] = (u32)(q2.y >> 32);
    lo[6] = (u32)q3.x; hi[6] = (u32)(q3.x >> 32);
    lo[7] = (u32)q3.y; hi[7] = (u32)(q3.y >> 32);

    float acc[8][8];
#pragma unroll
    for (int r = 0; r < 8; ++r)
#pragma unroll
        for (int k = 0; k < 8; ++k) acc[r][k] = 0.f;

    const float* yb = ys + ss * YSTRIDE + kh * 8;

#define JLOOP(CUR, YB)                                                  \
    _Pragma("unroll 4")                                                 \
    for (int j = 0; j < 32; ++j) {                                      \
        float yv[8];                                                    \
        *(float4*)&yv[0] = *(const float4*)((YB) + j * KK);             \
        *(float4*)&yv[4] = *(const float4*)((YB) + j * KK + 4);         \
        _Pragma("unroll")                                               \
        for (int r = 0; r < 8; ++r) {                                   \
            float f = (float)((CUR[r] >> j) & 1u);                      \
            _Pragma("unroll")                                           \
            for (int k = 0; k < 8; ++k) acc[r][k] += f * yv[k];         \
        }                                                               \
    }

    JLOOP(lo, yb)
    JLOOP(hi, yb + 32 * KK)
#undef JLOOP

    // reduce the 4 ss-slices (lane bits 4,5)
#pragma unroll
    for (int r = 0; r < 8; ++r)
#pragma unroll
        for (int k = 0; k < 8; ++k) {
            float a = acc[r][k];
            a += __shfl_xor(a, 16);
            a += __shfl_xor(a, 32);
            acc[r][k] = a;
        }

    if (ss == 0) {
        float* yo = yout + ((long)b * NN + row_base) * KK + kh * 8;
#pragma unroll
        for (int r = 0; r < 8; ++r)
#pragma unroll
            for (int k = 0; k < 8; ++k)
                atomicAdd(&yo[r * KK + k], acc[r][k]);
    }
}

// -------------------------------------------------------------- combine -----
__global__ void combine_kernel(const float* __restrict__ Y0,
                               const float* __restrict__ Yc,   // Y1|Y2|Y3
                               const float* __restrict__ ker,  // [C][T][K]
                               float* __restrict__ out) {
    __shared__ float4 eS[3][CC][KK / 4];
    int tid = threadIdx.x;
    if (tid < CC * (KK / 4)) {
        int c = tid >> 2, k4 = tid & 3;
        const float4* kf = (const float4*)ker;
        float4 a = kf[(c * TT + 0) * (KK / 4) + k4];
        float4 d = kf[(c * TT + 1) * (KK / 4) + k4];
        float4 e = kf[(c * TT + 2) * (KK / 4) + k4];
        float4 e1, e2, e3;
        e1.x = a.x + d.x + e.x;             e1.y = a.y + d.y + e.y;
        e1.z = a.z + d.z + e.z;             e1.w = a.w + d.w + e.w;
        e2.x = a.x*d.x + a.x*e.x + d.x*e.x; e2.y = a.y*d.y + a.y*e.y + d.y*e.y;
        e2.z = a.z*d.z + a.z*e.z + d.z*e.z; e2.w = a.w*d.w + a.w*e.w + d.w*e.w;
        e3.x = a.x * d.x * e.x;             e3.y = a.y * d.y * e.y;
        e3.z = a.z * d.z * e.z;             e3.w = a.w * d.w * e.w;
        eS[0][c][k4] = e1; eS[1][c][k4] = e2; eS[2][c][k4] = e3;
    }
    __syncthreads();

    int gid = blockIdx.x * blockDim.x + tid;
    if (gid >= BB * NN * (KK / 4)) return;
    int k4 = gid & 3;
    int n  = (gid >> 2) & (NN - 1);
    int b  = gid >> 14;
    const long YSZ = (long)BB * NN * KK / 4;
    long yi = (long)(b * NN + n) * (KK / 4) + k4;
    float4 y0 = ((const float4*)Y0)[yi];
    float4 y1 = ((const float4*)Yc)[yi];
    float4 y2 = ((const float4*)Yc)[YSZ + yi];
    float4 y3 = ((const float4*)Yc)[2 * YSZ + yi];
#pragma unroll
    for (int c = 0; c < CC; ++c) {
        float4 e1 = eS[0][c][k4], e2 = eS[1][c][k4], e3 = eS[2][c][k4];
        float4 r;
        r.x = y0.x + e1.x * y1.x + e2.x * y2.x + e3.x * y3.x;
        r.y = y0.y + e1.y * y1.y + e2.y * y2.y + e3.y * y3.y;
        r.z = y0.z + e1.z * y1.z + e2.z * y2.z + e3.z * y3.z;
        r.w = y0.w + e1.w * y1.w + e2.w * y2.w + e3.w * y3.w;
        ((float4*)out)[(long)((b * CC + c) * NN + n) * (KK / 4) + k4] = r;
    }
}

// --------------------------------------------------------------- launch -----
extern "C" void kernel_launch(void* const* d_in, const int* in_sizes, int n_in,
                              void* d_out, int out_size, void* d_ws, size_t ws_size,
                              hipStream_t stream) {
    const float* labels = (const float*)d_in[0];   // [B,N,K] f32
    const int*   lig    = (const int*)d_in[1];     // [B,N,N] i32
    const float* ker    = (const float*)d_in[2];   // [C,T,K] f32
    float* out  = (float*)d_out;
    u64*   bits = (u64*)d_out;                     // 8 MB scratch, exact fit
    float* Y1 = (float*)d_ws;
    float* Y2 = Y1 + (long)BB * NN * KK;
    float* Y3 = Y2 + (long)BB * NN * KK;

    hipLaunchKernelGGL(pack_kernel, dim3(2048), dim3(256), 0, stream, lig, bits);
    hipMemsetAsync(d_ws, 0, 3L * BB * NN * KK * sizeof(float), stream);

    dim3 sgrid(BB * (NN / ROWSB) * SCHUNKS);       // 1024 blocks
    hipLaunchKernelGGL(spmm_kernel, sgrid, dim3(256), 0, stream, bits, labels, Y1);
    hipLaunchKernelGGL(spmm_kernel, sgrid, dim3(256), 0, stream, bits, Y1, Y2);
    hipLaunchKernelGGL(spmm_kernel, sgrid, dim3(256), 0, stream, bits, Y2, Y3);

    hipLaunchKernelGGL(combine_kernel, dim3(BB * NN * (KK / 4) / 256), dim3(256),
                       0, stream, labels, Y1, ker, out);
}

// Round 3
// 462.969 us; speedup vs baseline: 1.8010x; 1.0153x over previous
//
#include <hip/hip_runtime.h>

// WL-conv factorized:  out[b,c,n,k] = Y0 + e1[c,k]*Y1 + e2[c,k]*Y2 + e3[c,k]*Y3
// with Ym = M^m labels (M = thresholded adjacency, c-independent) and e_m the
// elementary symmetric polynomials of kernels[c,0..2,k]. Valid because all
// per-step operators (I + k_t ∘ M) commute.
//
// d_out (8 MB): reused as TRANSPOSED packed bit-mask (word-major) scratch,
//               overwritten by the final combine kernel.
// d_ws (>=3 MB): Y1|Y2|Y3, each B*N*K f32 — zeroed by pack_kernel (the
//               hipMemsetAsync path cost 150 us/replay as fillBufferAligned).

#define BB 4
#define NN 4096
#define KK 16
#define CC 8
#define TT 3
#define WPR (NN / 64)

typedef unsigned long long u64;
typedef unsigned int u32;

// ---------------------------------------------------------------- pack ------
// TRANSPOSED: bits[(b*WPR + w)*NN + n] bit j <-> (lig[b][n][w*64+j] >= 1)
// Also zeroes the 3 MB Y workspace (runs before spmm1 on the same stream).
__global__ void pack_kernel(const int* __restrict__ lig, u64* __restrict__ bits,
                            float4* __restrict__ yzero) {
    const long total = (long)BB * WPR * NN;              // 1,048,576 words
    int  gid  = blockIdx.x * blockDim.x + threadIdx.x;
    if (gid < 3 * BB * NN * KK / 4)                      // 196,608 float4
        yzero[gid] = make_float4(0.f, 0.f, 0.f, 0.f);
    long wid  = ((long)gid) >> 6;
    int  lane = threadIdx.x & 63;
    long nw   = ((long)gridDim.x * blockDim.x) >> 6;
    for (long o = wid; o < total; o += nw) {
        int n = (int)(o & (NN - 1));
        int w = (int)((o >> 12) & (WPR - 1));
        int b = (int)(o >> 18);
        int v = lig[((long)b * NN + n) * NN + (w << 6) + lane];
        u64 m = __ballot(v >= 1);
        if (lane == 0) bits[o] = m;
    }
}

// ---------------------------------------------------------------- spmm ------
// yout += M * yin restricted to (row-block, s-chunk); yout pre-zeroed.
// grid = BB * (NN/ROWSB=16) * SCHUNKS=16 = 1024 blocks of 256 threads.
// lane layout: kh = bit0 (k-half), rg_lo = bits1-3, ss = bits4-5 (s-slice);
// wave W = tid>>6;  rg = W*8+rg_lo (32 groups x 8 rows = 256 rows/block).
// Each thread: 8 rows x 8 k accumulators over its 64-s word; ss-slices
// reduced with __shfl_xor(16/32); one atomicAdd per (row,k) per chunk.
#define SCHUNKS 16
#define SLEN 256
#define ROWSB 256

// y LDS layout: per 64-s block: 64*16 floats + 4 pad floats (breaks the
// ss-stride-4096B bank alias; b128 reads stay <=2-way which is free).
#define YSTRIDE 1028   // floats per 64-s block

__global__ __launch_bounds__(256, 4)
void spmm_kernel(const u64* __restrict__ bits,
                 const float* __restrict__ yin,
                 float* __restrict__ yout) {
    __shared__ float ys[4 * YSTRIDE];                    // 16448 B
    int bid = blockIdx.x;
    int sc  = bid & (SCHUNKS - 1);
    int rb  = (bid >> 4) & (NN / ROWSB - 1);
    int b   = bid >> 8;
    int tid = threadIdx.x;
    int s0  = sc * SLEN;

    // stage Y[s0..s0+255][0..15], padded every 64 s (float4 i -> i + (i>>8))
    const float4* ysrc = (const float4*)(yin + ((long)b * NN + s0) * KK);
    for (int i = tid; i < SLEN * KK / 4; i += 256)
        ((float4*)ys)[i + (i >> 8)] = ysrc[i];
    __syncthreads();

    const int kh    = tid & 1;
    const int rg_lo = (tid >> 1) & 7;
    const int ss    = (tid >> 4) & 3;
    const int W     = tid >> 6;
    const int rg    = W * 8 + rg_lo;
    const int row_base = rb * ROWSB + rg * 8;
    const int wglob = (s0 >> 6) + ss;

    // 8 consecutive row-masks for this word: one contiguous 64 B
    const ulonglong2* bp =
        (const ulonglong2*)(bits + (long)(b * WPR + wglob) * NN + row_base);
    ulonglong2 q0 = bp[0], q1 = bp[1], q2 = bp[2], q3 = bp[3];
    u32 lo[8], hi[8];
    lo[0] = (u32)q0.x; hi[0] = (u32)(q0.x >> 32);
    lo[1] = (u32)q0.y; hi[1] = (u32)(q0.y >> 32);
    lo[2] = (u32)q1.x; hi[2] = (u32)(q1.x >> 32);
    lo[3] = (u32)q1.y; hi[3] = (u32)(q1.y >> 32);
    lo[4] = (u32)q2.x; hi[4] = (u32)(q2.x >> 32);
    lo[5] = (u32)q2.y; hi[5] = (u32)(q2.y >> 32);
    lo[6] = (u32)q3.x; hi[6] = (u32)(q3.x >> 32);
    lo[7] = (u32)q3.y; hi[7] = (u32)(q3.y >> 32);

    float acc[8][8];
#pragma unroll
    for (int r = 0; r < 8; ++r)
#pragma unroll
        for (int k = 0; k < 8; ++k) acc[r][k] = 0.f;

    const float* yb = ys + ss * YSTRIDE + kh * 8;

#define JLOOP(CUR, YB)                                                  \
    _Pragma("unroll 4")                                                 \
    for (int j = 0; j < 32; ++j) {                                      \
        float yv[8];                                                    \
        *(float4*)&yv[0] = *(const float4*)((YB) + j * KK);             \
        *(float4*)&yv[4] = *(const float4*)((YB) + j * KK + 4);         \
        _Pragma("unroll")                                               \
        for (int r = 0; r < 8; ++r) {                                   \
            float f = (float)((CUR[r] >> j) & 1u);                      \
            _Pragma("unroll")                                           \
            for (int k = 0; k < 8; ++k) acc[r][k] += f * yv[k];         \
        }                                                               \
    }

    JLOOP(lo, yb)
    JLOOP(hi, yb + 32 * KK)
#undef JLOOP

    // reduce the 4 ss-slices (lane bits 4,5)
#pragma unroll
    for (int r = 0; r < 8; ++r)
#pragma unroll
        for (int k = 0; k < 8; ++k) {
            float a = acc[r][k];
            a += __shfl_xor(a, 16);
            a += __shfl_xor(a, 32);
            acc[r][k] = a;
        }

    if (ss == 0) {
        float* yo = yout + ((long)b * NN + row_base) * KK + kh * 8;
#pragma unroll
        for (int r = 0; r < 8; ++r)
#pragma unroll
            for (int k = 0; k < 8; ++k)
                atomicAdd(&yo[r * KK + k], acc[r][k]);
    }
}

// -------------------------------------------------------------- combine -----
__global__ void combine_kernel(const float* __restrict__ Y0,
                               const float* __restrict__ Yc,   // Y1|Y2|Y3
                               const float* __restrict__ ker,  // [C][T][K]
                               float* __restrict__ out) {
    __shared__ float4 eS[3][CC][KK / 4];
    int tid = threadIdx.x;
    if (tid < CC * (KK / 4)) {
        int c = tid >> 2, k4 = tid & 3;
        const float4* kf = (const float4*)ker;
        float4 a = kf[(c * TT + 0) * (KK / 4) + k4];
        float4 d = kf[(c * TT + 1) * (KK / 4) + k4];
        float4 e = kf[(c * TT + 2) * (KK / 4) + k4];
        float4 e1, e2, e3;
        e1.x = a.x + d.x + e.x;             e1.y = a.y + d.y + e.y;
        e1.z = a.z + d.z + e.z;             e1.w = a.w + d.w + e.w;
        e2.x = a.x*d.x + a.x*e.x + d.x*e.x; e2.y = a.y*d.y + a.y*e.y + d.y*e.y;
        e2.z = a.z*d.z + a.z*e.z + d.z*e.z; e2.w = a.w*d.w + a.w*e.w + d.w*e.w;
        e3.x = a.x * d.x * e.x;             e3.y = a.y * d.y * e.y;
        e3.z = a.z * d.z * e.z;             e3.w = a.w * d.w * e.w;
        eS[0][c][k4] = e1; eS[1][c][k4] = e2; eS[2][c][k4] = e3;
    }
    __syncthreads();

    int gid = blockIdx.x * blockDim.x + tid;
    if (gid >= BB * NN * (KK / 4)) return;
    int k4 = gid & 3;
    int n  = (gid >> 2) & (NN - 1);
    int b  = gid >> 14;
    const long YSZ = (long)BB * NN * KK / 4;
    long yi = (long)(b * NN + n) * (KK / 4) + k4;
    float4 y0 = ((const float4*)Y0)[yi];
    float4 y1 = ((const float4*)Yc)[yi];
    float4 y2 = ((const float4*)Yc)[YSZ + yi];
    float4 y3 = ((const float4*)Yc)[2 * YSZ + yi];
#pragma unroll
    for (int c = 0; c < CC; ++c) {
        float4 e1 = eS[0][c][k4], e2 = eS[1][c][k4], e3 = eS[2][c][k4];
        float4 r;
        r.x = y0.x + e1.x * y1.x + e2.x * y2.x + e3.x * y3.x;
        r.y = y0.y + e1.y * y1.y + e2.y * y2.y + e3.y * y3.y;
        r.z = y0.z + e1.z * y1.z + e2.z * y2.z + e3.z * y3.z;
        r.w = y0.w + e1.w * y1.w + e2.w * y2.w + e3.w * y3.w;
        ((float4*)out)[(long)((b * CC + c) * NN + n) * (KK / 4) + k4] = r;
    }
}

// --------------------------------------------------------------- launch -----
extern "C" void kernel_launch(void* const* d_in, const int* in_sizes, int n_in,
                              void* d_out, int out_size, void* d_ws, size_t ws_size,
                              hipStream_t stream) {
    const float* labels = (const float*)d_in[0];   // [B,N,K] f32
    const int*   lig    = (const int*)d_in[1];     // [B,N,N] i32
    const float* ker    = (const float*)d_in[2];   // [C,T,K] f32
    float* out  = (float*)d_out;
    u64*   bits = (u64*)d_out;                     // 8 MB scratch, exact fit
    float* Y1 = (float*)d_ws;
    float* Y2 = Y1 + (long)BB * NN * KK;
    float* Y3 = Y2 + (long)BB * NN * KK;

    hipLaunchKernelGGL(pack_kernel, dim3(2048), dim3(256), 0, stream,
                       lig, bits, (float4*)d_ws);

    dim3 sgrid(BB * (NN / ROWSB) * SCHUNKS);       // 1024 blocks
    hipLaunchKernelGGL(spmm_kernel, sgrid, dim3(256), 0, stream, bits, labels, Y1);
    hipLaunchKernelGGL(spmm_kernel, sgrid, dim3(256), 0, stream, bits, Y1, Y2);
    hipLaunchKernelGGL(spmm_kernel, sgrid, dim3(256), 0, stream, bits, Y2, Y3);

    hipLaunchKernelGGL(combine_kernel, dim3(BB * NN * (KK / 4) / 256), dim3(256),
                       0, stream, labels, Y1, ker, out);
}

// Round 4
// 298.391 us; speedup vs baseline: 2.7943x; 1.5515x over previous
//
#include <hip/hip_runtime.h>

// WL-conv factorized:  out[b,c,n,k] = Y0 + e1[c,k]*Y1 + e2[c,k]*Y2 + e3[c,k]*Y3
// with Ym = M^m labels (M = thresholded adjacency, c-independent) and e_m the
// elementary symmetric polynomials of kernels[c,0..2,k]. Valid because all
// per-step operators (I + k_t ∘ M) commute.
//
// d_out (8 MB): reused as TRANSPOSED packed bit-mask (word-major) scratch,
//               overwritten by the final combine kernel.
// d_ws (>=3 MB): Y1|Y2|Y3, each B*N*K f32 — zeroed inside pack_kernel.
//
// spmm redesign vs R2: per-thread state cut to 32 acc (8 rows x 4 k) so the
// kernel provably fits the 128-VGPR cap (R1/R2 were spill-bound: dur halved
// exactly when the cap doubled).

#define BB 4
#define NN 4096
#define KK 16
#define CC 8
#define TT 3
#define WPR (NN / 64)

typedef unsigned long long u64;
typedef unsigned int u32;

// ---------------------------------------------------------------- pack ------
// TRANSPOSED: bits[(b*WPR + w)*NN + n] bit j <-> (lig[b][n][w*64+j] >= 1)
// Also zeroes the 3 MB Y workspace (runs before spmm1 on the same stream).
__global__ void pack_kernel(const int* __restrict__ lig, u64* __restrict__ bits,
                            float4* __restrict__ yzero) {
    const long total = (long)BB * WPR * NN;              // 1,048,576 words
    int  gid  = blockIdx.x * blockDim.x + threadIdx.x;
    if (gid < 3 * BB * NN * KK / 4)                      // 196,608 float4
        yzero[gid] = make_float4(0.f, 0.f, 0.f, 0.f);
    long wid  = ((long)gid) >> 6;
    int  lane = threadIdx.x & 63;
    long nw   = ((long)gridDim.x * blockDim.x) >> 6;
    for (long o = wid; o < total; o += nw) {
        int n = (int)(o & (NN - 1));
        int w = (int)((o >> 12) & (WPR - 1));
        int b = (int)(o >> 18);
        int v = lig[((long)b * NN + n) * NN + (w << 6) + lane];
        u64 m = __ballot(v >= 1);
        if (lane == 0) bits[o] = m;
    }
}

// ---------------------------------------------------------------- spmm ------
// yout += M * yin restricted to (256-row block, 256-s chunk); yout pre-zeroed.
// grid = BB * (NN/ROWSB=16) * SCHUNKS=16 = 1024 blocks of 256 threads
//      = exactly 4 resident blocks/CU (no tail).
// lane bits: kq = 0-1 (k-quarter, 4 floats), rg_lo = 2-4, ss = 5 (s-slice);
// wave W = tid>>6; rg = W*8+rg_lo (32 groups x 8 rows = 256 rows/block).
// Each thread: 8 rows x 4 k acc over 2 sub-chunks (its ss word of each);
// ss pair reduced with one __shfl_xor(32); one atomicAdd per (row,k,chunk).
#define SCHUNKS 16
#define SLEN 256
#define ROWSB 256
#define YSTRIDE 1028   // floats per 64-s word (+1 float4 pad: <=2-way LDS, free)

__global__ __launch_bounds__(256, 4)
void spmm_kernel(const u64* __restrict__ bits,
                 const float* __restrict__ yin,
                 float* __restrict__ yout) {
    __shared__ float ys[4 * YSTRIDE];                    // 16448 B
    int bid = blockIdx.x;
    int sc  = bid & (SCHUNKS - 1);
    int rb  = (bid >> 4) & (NN / ROWSB - 1);
    int b   = bid >> 8;
    int tid = threadIdx.x;
    int s0  = sc * SLEN;

    // stage Y[s0..s0+255][0..15], padded every 64 s (float4 i -> i + (i>>8))
    const float4* ysrc = (const float4*)(yin + ((long)b * NN + s0) * KK);
    for (int i = tid; i < SLEN * KK / 4; i += 256)
        ((float4*)ys)[i + (i >> 8)] = ysrc[i];
    __syncthreads();

    const int kq    = tid & 3;
    const int rg_lo = (tid >> 2) & 7;
    const int ss    = (tid >> 5) & 1;
    const int W     = tid >> 6;
    const int rg    = W * 8 + rg_lo;
    const int row_base = rb * ROWSB + rg * 8;

    float acc[8][4];
#pragma unroll
    for (int r = 0; r < 8; ++r)
#pragma unroll
        for (int k = 0; k < 4; ++k) acc[r][k] = 0.f;

#define JLOOP(CUR, YB)                                                  \
    _Pragma("unroll 4")                                                 \
    for (int j = 0; j < 32; ++j) {                                      \
        float4 yv = *(const float4*)((YB) + j * KK);                    \
        _Pragma("unroll")                                               \
        for (int r = 0; r < 8; ++r) {                                   \
            float f = (float)((CUR[r] >> j) & 1u);                      \
            acc[r][0] += f * yv.x; acc[r][1] += f * yv.y;               \
            acc[r][2] += f * yv.z; acc[r][3] += f * yv.w;               \
        }                                                               \
    }

#pragma unroll
    for (int sub = 0; sub < 2; ++sub) {
        const int word  = sub * 2 + ss;                  // word within chunk
        const int wglob = sc * 4 + word;
        // 8 consecutive row-masks for this word: one contiguous 64 B
        const ulonglong2* bp =
            (const ulonglong2*)(bits + (long)(b * WPR + wglob) * NN + row_base);
        ulonglong2 q0 = bp[0], q1 = bp[1], q2 = bp[2], q3 = bp[3];
        u32 lo[8], hi[8];
        lo[0] = (u32)q0.x; hi[0] = (u32)(q0.x >> 32);
        lo[1] = (u32)q0.y; hi[1] = (u32)(q0.y >> 32);
        lo[2] = (u32)q1.x; hi[2] = (u32)(q1.x >> 32);
        lo[3] = (u32)q1.y; hi[3] = (u32)(q1.y >> 32);
        lo[4] = (u32)q2.x; hi[4] = (u32)(q2.x >> 32);
        lo[5] = (u32)q2.y; hi[5] = (u32)(q2.y >> 32);
        lo[6] = (u32)q3.x; hi[6] = (u32)(q3.x >> 32);
        lo[7] = (u32)q3.y; hi[7] = (u32)(q3.y >> 32);

        const float* yb = ys + word * YSTRIDE + kq * 4;
        JLOOP(lo, yb)
        JLOOP(hi, yb + 32 * KK)
    }
#undef JLOOP

    // reduce the ss pair (lane bit 5)
#pragma unroll
    for (int r = 0; r < 8; ++r)
#pragma unroll
        for (int k = 0; k < 4; ++k) {
            float a = acc[r][k];
            a += __shfl_xor(a, 32);
            acc[r][k] = a;
        }

    if (ss == 0) {
        float* yo = yout + ((long)b * NN + row_base) * KK + kq * 4;
#pragma unroll
        for (int r = 0; r < 8; ++r)
#pragma unroll
            for (int k = 0; k < 4; ++k)
                atomicAdd(&yo[r * KK + k], acc[r][k]);
    }
}

// -------------------------------------------------------------- combine -----
__global__ void combine_kernel(const float* __restrict__ Y0,
                               const float* __restrict__ Yc,   // Y1|Y2|Y3
                               const float* __restrict__ ker,  // [C][T][K]
                               float* __restrict__ out) {
    __shared__ float4 eS[3][CC][KK / 4];
    int tid = threadIdx.x;
    if (tid < CC * (KK / 4)) {
        int c = tid >> 2, k4 = tid & 3;
        const float4* kf = (const float4*)ker;
        float4 a = kf[(c * TT + 0) * (KK / 4) + k4];
        float4 d = kf[(c * TT + 1) * (KK / 4) + k4];
        float4 e = kf[(c * TT + 2) * (KK / 4) + k4];
        float4 e1, e2, e3;
        e1.x = a.x + d.x + e.x;             e1.y = a.y + d.y + e.y;
        e1.z = a.z + d.z + e.z;             e1.w = a.w + d.w + e.w;
        e2.x = a.x*d.x + a.x*e.x + d.x*e.x; e2.y = a.y*d.y + a.y*e.y + d.y*e.y;
        e2.z = a.z*d.z + a.z*e.z + d.z*e.z; e2.w = a.w*d.w + a.w*e.w + d.w*e.w;
        e3.x = a.x * d.x * e.x;             e3.y = a.y * d.y * e.y;
        e3.z = a.z * d.z * e.z;             e3.w = a.w * d.w * e.w;
        eS[0][c][k4] = e1; eS[1][c][k4] = e2; eS[2][c][k4] = e3;
    }
    __syncthreads();

    int gid = blockIdx.x * blockDim.x + tid;
    if (gid >= BB * NN * (KK / 4)) return;
    int k4 = gid & 3;
    int n  = (gid >> 2) & (NN - 1);
    int b  = gid >> 14;
    const long YSZ = (long)BB * NN * KK / 4;
    long yi = (long)(b * NN + n) * (KK / 4) + k4;
    float4 y0 = ((const float4*)Y0)[yi];
    float4 y1 = ((const float4*)Yc)[yi];
    float4 y2 = ((const float4*)Yc)[YSZ + yi];
    float4 y3 = ((const float4*)Yc)[2 * YSZ + yi];
#pragma unroll
    for (int c = 0; c < CC; ++c) {
        float4 e1 = eS[0][c][k4], e2 = eS[1][c][k4], e3 = eS[2][c][k4];
        float4 r;
        r.x = y0.x + e1.x * y1.x + e2.x * y2.x + e3.x * y3.x;
        r.y = y0.y + e1.y * y1.y + e2.y * y2.y + e3.y * y3.y;
        r.z = y0.z + e1.z * y1.z + e2.z * y2.z + e3.z * y3.z;
        r.w = y0.w + e1.w * y1.w + e2.w * y2.w + e3.w * y3.w;
        ((float4*)out)[(long)((b * CC + c) * NN + n) * (KK / 4) + k4] = r;
    }
}

// --------------------------------------------------------------- launch -----
extern "C" void kernel_launch(void* const* d_in, const int* in_sizes, int n_in,
                              void* d_out, int out_size, void* d_ws, size_t ws_size,
                              hipStream_t stream) {
    const float* labels = (const float*)d_in[0];   // [B,N,K] f32
    const int*   lig    = (const int*)d_in[1];     // [B,N,N] i32
    const float* ker    = (const float*)d_in[2];   // [C,T,K] f32
    float* out  = (float*)d_out;
    u64*   bits = (u64*)d_out;                     // 8 MB scratch, exact fit
    float* Y1 = (float*)d_ws;
    float* Y2 = Y1 + (long)BB * NN * KK;
    float* Y3 = Y2 + (long)BB * NN * KK;

    hipLaunchKernelGGL(pack_kernel, dim3(2048), dim3(256), 0, stream,
                       lig, bits, (float4*)d_ws);

    dim3 sgrid(BB * (NN / ROWSB) * SCHUNKS);       // 1024 blocks
    hipLaunchKernelGGL(spmm_kernel, sgrid, dim3(256), 0, stream, bits, labels, Y1);
    hipLaunchKernelGGL(spmm_kernel, sgrid, dim3(256), 0, stream, bits, Y1, Y2);
    hipLaunchKernelGGL(spmm_kernel, sgrid, dim3(256), 0, stream, bits, Y2, Y3);

    hipLaunchKernelGGL(combine_kernel, dim3(BB * NN * (KK / 4) / 256), dim3(256),
                       0, stream, labels, Y1, ker, out);
}

// Round 5
// 129.074 us; speedup vs baseline: 6.4599x; 2.3118x over previous
//
#include <hip/hip_runtime.h>

// WL-conv factorized:  out[b,c,n,k] = Y0 + e1[c,k]*Y1 + e2[c,k]*Y2 + e3[c,k]*Y3
// with Ym = M^m labels (M = thresholded adjacency, c-independent) and e_m the
// elementary symmetric polynomials of kernels[c,0..2,k]. Valid because all
// per-step operators (I + k_t ∘ M) commute.
//
// spmm now on the MATRIX pipe: Y_next = M·Y as mfma_f32_16x16x32_bf16.
//  - M bits -> bf16 A-fragments via 256x16B LDS lookup (byte -> 8 bf16 0/1)
//  - Y split hi/lo bf16 (error ~2^-18 rel, fp32-grade), 2 MFMAs share one A
//  - s split 8-way across blocks, merged with f32 atomicAdd (Y pre-zeroed)
//
// d_out (8 MB): TRANSPOSED packed bits (word-major), overwritten by combine.
// d_ws (>=3 MB): Y1|Y2|Y3 f32, zeroed inside pack_kernel.

#define BB 4
#define NN 4096
#define KK 16
#define CC 8
#define TT 3
#define WPR (NN / 64)

typedef unsigned long long u64;
typedef unsigned int u32;
typedef __attribute__((ext_vector_type(8))) short s16x8;
typedef __attribute__((ext_vector_type(4))) float f32x4v;

// ---------------------------------------------------------------- pack ------
// TRANSPOSED: bits[(b*WPR + w)*NN + n] bit j <-> (lig[b][n][w*64+j] >= 1)
// Also zeroes the 3 MB Y workspace.
__global__ void pack_kernel(const int* __restrict__ lig, u64* __restrict__ bits,
                            float4* __restrict__ yzero) {
    const long total = (long)BB * WPR * NN;              // 1,048,576 words
    int  gid  = blockIdx.x * blockDim.x + threadIdx.x;
    if (gid < 3 * BB * NN * KK / 4)                      // 196,608 float4
        yzero[gid] = make_float4(0.f, 0.f, 0.f, 0.f);
    long wid  = ((long)gid) >> 6;
    int  lane = threadIdx.x & 63;
    long nw   = ((long)gridDim.x * blockDim.x) >> 6;
    for (long o = wid; o < total; o += nw) {
        int n = (int)(o & (NN - 1));
        int w = (int)((o >> 12) & (WPR - 1));
        int b = (int)(o >> 18);
        int v = lig[((long)b * NN + n) * NN + (w << 6) + lane];
        u64 m = __ballot(v >= 1);
        if (lane == 0) bits[o] = m;
    }
}

// ----------------------------------------------------------- spmm (MFMA) ----
// grid = BB * 16 rowblocks(256 rows) * 8 s-slices(512 s) = 512 blocks,
// 256 threads = 4 waves; wave owns 4 row-tiles (64 rows) x 16 features.
// Per k-tile (32 s): byte-extract + table ds_read_b128 -> A (shared by hi/lo
// MFMA); B hi/lo frags from transposed LDS Y. atomicAdd merge across slices.
#define SSL 512
#define NSLICE 8
#define RBLK 256

__device__ __forceinline__ u32 bf16_rne(float f) {
    u32 u = __float_as_uint(f);
    return (u + 0x7FFFu + ((u >> 16) & 1u)) >> 16;
}

__global__ __launch_bounds__(256, 2)
void spmm_mfma(const u64* __restrict__ bits, const float* __restrict__ yin,
               float* __restrict__ yout) {
    __shared__ u32 tab[256 * 4];                 // byte -> 8 bf16 (0/1)
    __shared__ unsigned short yh[KK][SSL + 8];   // hi bf16, [feature][s]
    __shared__ unsigned short yl[KK][SSL + 8];   // lo bf16

    const int bid = blockIdx.x;
    const int ss  = bid & (NSLICE - 1);
    const int rb  = (bid >> 3) & 15;
    const int b   = bid >> 7;
    const int tid = threadIdx.x;

    // byte -> 8x bf16 lookup table (one entry per thread)
    {
        const u32 e = tid;
        tab[e * 4 + 0] = ((e & 1u)   ? 0x3F80u : 0u) | ((e & 2u)   ? 0x3F800000u : 0u);
        tab[e * 4 + 1] = ((e & 4u)   ? 0x3F80u : 0u) | ((e & 8u)   ? 0x3F800000u : 0u);
        tab[e * 4 + 2] = ((e & 16u)  ? 0x3F80u : 0u) | ((e & 32u)  ? 0x3F800000u : 0u);
        tab[e * 4 + 3] = ((e & 64u)  ? 0x3F80u : 0u) | ((e & 128u) ? 0x3F800000u : 0u);
    }

    // stage Y slice hi/lo bf16, transposed [feature][s]
    const float* yb = yin + ((long)b * NN + ss * SSL) * KK;
#pragma unroll
    for (int it = 0; it < 4; ++it) {
        int task = tid + it * 256;               // 0..1023
        int fq = task & 3;                       // feature quad
        int sp = task >> 2;                      // s-pair 0..255
        float4 ya = *(const float4*)(yb + (2 * sp) * KK + fq * 4);
        float4 yc = *(const float4*)(yb + (2 * sp + 1) * KK + fq * 4);
        const float* pa = &ya.x;
        const float* pc = &yc.x;
#pragma unroll
        for (int f = 0; f < 4; ++f) {
            float a = pa[f], c = pc[f];
            u32 ha = bf16_rne(a);
            u32 hc = bf16_rne(c);
            u32 la = bf16_rne(a - __uint_as_float(ha << 16));
            u32 lc = bf16_rne(c - __uint_as_float(hc << 16));
            *(u32*)&yh[fq * 4 + f][2 * sp] = ha | (hc << 16);
            *(u32*)&yl[fq * 4 + f][2 * sp] = la | (lc << 16);
        }
    }
    __syncthreads();

    const int lane = tid & 63;
    const int W    = tid >> 6;
    const int n16  = lane & 15;                  // A row-in-tile / B feature
    const int g    = lane >> 4;                  // k-subgroup (8 elems)
    const int gsh  = g * 8;
    const int row0 = rb * RBLK + W * 64;

    f32x4v acc[4];
#pragma unroll
    for (int rt = 0; rt < 4; ++rt) acc[rt] = (f32x4v){0.f, 0.f, 0.f, 0.f};

    const u64* bb = bits + ((long)(b * WPR + ss * (SSL / 64))) * NN + row0 + n16;

    u64 wc[4], wn[4];
#pragma unroll
    for (int rt = 0; rt < 4; ++rt) wc[rt] = bb[rt * 16];

#pragma unroll
    for (int w = 0; w < SSL / 64; ++w) {
        if (w + 1 < SSL / 64) {
#pragma unroll
            for (int rt = 0; rt < 4; ++rt) wn[rt] = bb[(long)(w + 1) * NN + rt * 16];
        }
#pragma unroll
        for (int kh = 0; kh < 2; ++kh) {
            const int koff = w * 64 + kh * 32 + gsh;
            s16x8 bhi = *(const s16x8*)&yh[n16][koff];
            s16x8 blo = *(const s16x8*)&yl[n16][koff];
#pragma unroll
            for (int rt = 0; rt < 4; ++rt) {
                u32 half = kh ? (u32)(wc[rt] >> 32) : (u32)wc[rt];
                u32 byt  = (half >> gsh) & 0xFFu;
                s16x8 a  = *(const s16x8*)&tab[byt * 4];
                acc[rt] = __builtin_amdgcn_mfma_f32_16x16x32_bf16(a, bhi, acc[rt], 0, 0, 0);
                acc[rt] = __builtin_amdgcn_mfma_f32_16x16x32_bf16(a, blo, acc[rt], 0, 0, 0);
            }
        }
#pragma unroll
        for (int rt = 0; rt < 4; ++rt) wc[rt] = wn[rt];
    }

    // D[m][n]: n = lane&15 (feature), m = 4*(lane>>4)+r (row in tile)
    float* yo = yout + ((long)b * NN + row0) * KK + n16;
#pragma unroll
    for (int rt = 0; rt < 4; ++rt)
#pragma unroll
        for (int r = 0; r < 4; ++r)
            atomicAdd(&yo[(rt * 16 + 4 * g + r) * KK], acc[rt][r]);
}

// -------------------------------------------------------------- combine -----
__global__ void combine_kernel(const float* __restrict__ Y0,
                               const float* __restrict__ Yc,   // Y1|Y2|Y3
                               const float* __restrict__ ker,  // [C][T][K]
                               float* __restrict__ out) {
    __shared__ float4 eS[3][CC][KK / 4];
    int tid = threadIdx.x;
    if (tid < CC * (KK / 4)) {
        int c = tid >> 2, k4 = tid & 3;
        const float4* kf = (const float4*)ker;
        float4 a = kf[(c * TT + 0) * (KK / 4) + k4];
        float4 d = kf[(c * TT + 1) * (KK / 4) + k4];
        float4 e = kf[(c * TT + 2) * (KK / 4) + k4];
        float4 e1, e2, e3;
        e1.x = a.x + d.x + e.x;             e1.y = a.y + d.y + e.y;
        e1.z = a.z + d.z + e.z;             e1.w = a.w + d.w + e.w;
        e2.x = a.x*d.x + a.x*e.x + d.x*e.x; e2.y = a.y*d.y + a.y*e.y + d.y*e.y;
        e2.z = a.z*d.z + a.z*e.z + d.z*e.z; e2.w = a.w*d.w + a.w*e.w + d.w*e.w;
        e3.x = a.x * d.x * e.x;             e3.y = a.y * d.y * e.y;
        e3.z = a.z * d.z * e.z;             e3.w = a.w * d.w * e.w;
        eS[0][c][k4] = e1; eS[1][c][k4] = e2; eS[2][c][k4] = e3;
    }
    __syncthreads();

    int gid = blockIdx.x * blockDim.x + tid;
    if (gid >= BB * NN * (KK / 4)) return;
    int k4 = gid & 3;
    int n  = (gid >> 2) & (NN - 1);
    int b  = gid >> 14;
    const long YSZ = (long)BB * NN * KK / 4;
    long yi = (long)(b * NN + n) * (KK / 4) + k4;
    float4 y0 = ((const float4*)Y0)[yi];
    float4 y1 = ((const float4*)Yc)[yi];
    float4 y2 = ((const float4*)Yc)[YSZ + yi];
    float4 y3 = ((const float4*)Yc)[2 * YSZ + yi];
#pragma unroll
    for (int c = 0; c < CC; ++c) {
        float4 e1 = eS[0][c][k4], e2 = eS[1][c][k4], e3 = eS[2][c][k4];
        float4 r;
        r.x = y0.x + e1.x * y1.x + e2.x * y2.x + e3.x * y3.x;
        r.y = y0.y + e1.y * y1.y + e2.y * y2.y + e3.y * y3.y;
        r.z = y0.z + e1.z * y1.z + e2.z * y2.z + e3.z * y3.z;
        r.w = y0.w + e1.w * y1.w + e2.w * y2.w + e3.w * y3.w;
        ((float4*)out)[(long)((b * CC + c) * NN + n) * (KK / 4) + k4] = r;
    }
}

// --------------------------------------------------------------- launch -----
extern "C" void kernel_launch(void* const* d_in, const int* in_sizes, int n_in,
                              void* d_out, int out_size, void* d_ws, size_t ws_size,
                              hipStream_t stream) {
    const float* labels = (const float*)d_in[0];   // [B,N,K] f32
    const int*   lig    = (const int*)d_in[1];     // [B,N,N] i32
    const float* ker    = (const float*)d_in[2];   // [C,T,K] f32
    float* out  = (float*)d_out;
    u64*   bits = (u64*)d_out;                     // 8 MB scratch, exact fit
    float* Y1 = (float*)d_ws;
    float* Y2 = Y1 + (long)BB * NN * KK;
    float* Y3 = Y2 + (long)BB * NN * KK;

    hipLaunchKernelGGL(pack_kernel, dim3(2048), dim3(256), 0, stream,
                       lig, bits, (float4*)d_ws);

    dim3 sgrid(BB * 16 * NSLICE);                  // 512 blocks
    hipLaunchKernelGGL(spmm_mfma, sgrid, dim3(256), 0, stream, bits, labels, Y1);
    hipLaunchKernelGGL(spmm_mfma, sgrid, dim3(256), 0, stream, bits, Y1, Y2);
    hipLaunchKernelGGL(spmm_mfma, sgrid, dim3(256), 0, stream, bits, Y2, Y3);

    hipLaunchKernelGGL(combine_kernel, dim3(BB * NN * (KK / 4) / 256), dim3(256),
                       0, stream, labels, Y1, ker, out);
}